// Round 1
// baseline (2261.681 us; speedup 1.0000x reference)
//
#include <hip/hip_runtime.h>
#include <hip/hip_fp16.h>
#include <stdint.h>

#define D_IN   768
#define D_SAE  12288
#define BATCH  8192
#define K_TOP  64

typedef _Float16 f16;
typedef _Float16 v8h __attribute__((ext_vector_type(8)));
typedef float v4f __attribute__((ext_vector_type(4)));

// ---------------- async global->LDS (16B/lane, wave-uniform LDS base) ----------------
__device__ inline void async16(const void* g, void* l) {
    __builtin_amdgcn_global_load_lds(
        (const __attribute__((address_space(1))) unsigned int*)g,
        (__attribute__((address_space(3))) unsigned int*)l, 16, 0, 0);
}

// ---------------- convert x: (x - b_dec) -> f16 hi/lo planes [BATCH][D_IN] ----------------
__global__ __launch_bounds__(256) void k_convert_x(
    const float* __restrict__ x, const float* __restrict__ b_dec,
    f16* __restrict__ xhi, f16* __restrict__ xlo)
{
    int i4 = (blockIdx.x * 256 + threadIdx.x) * 4;
    float4 v = *(const float4*)(x + i4);
    int col = i4 % D_IN;
    float vv[4] = { v.x - b_dec[col], v.y - b_dec[col + 1],
                    v.z - b_dec[col + 2], v.w - b_dec[col + 3] };
    union { short4 s; f16 h[4]; } H, L;
#pragma unroll
    for (int u = 0; u < 4; ++u) {
        H.h[u] = (f16)vv[u];
        L.h[u] = (f16)(vv[u] - (float)H.h[u]);
    }
    *(short4*)(xhi + i4) = H.s;
    *(short4*)(xlo + i4) = L.s;
}

// ---------------- convert+transpose W_enc [D_IN][D_SAE] -> hi/lo planes [D_SAE][D_IN] ----------------
__global__ __launch_bounds__(256) void k_convert_wt(
    const float* __restrict__ W, f16* __restrict__ whiT, f16* __restrict__ wloT)
{
    __shared__ float tile[32][33];
    const int n0 = blockIdx.x * 32;
    const int k0 = blockIdx.y * 32;
    const int c = threadIdx.x & 31;
    const int rr = threadIdx.x >> 5;   // 0..7
#pragma unroll
    for (int s = 0; s < 4; ++s) {
        int r = s * 8 + rr;
        tile[r][c] = W[(size_t)(k0 + r) * D_SAE + n0 + c];
    }
    __syncthreads();
#pragma unroll
    for (int s = 0; s < 4; ++s) {
        int r2 = s * 8 + rr;                 // n within tile
        float v = tile[c][r2];               // W[k0+c][n0+r2]
        f16 hi = (f16)v;
        f16 lo = (f16)(v - (float)hi);
        whiT[(size_t)(n0 + r2) * D_IN + k0 + c] = hi;
        wloT[(size_t)(n0 + r2) * D_IN + k0 + c] = lo;
    }
}

// ---------------- approximate encode GEMM (f16 MFMA, m97-style) ----------------
// out[m][n] = relu( sum_k A[m][k]*Bt[n][k] + b_enc[n] )   (approx, f16 inputs)
__global__ __launch_bounds__(256) void k_gemm_f16(
    const f16* __restrict__ A,    // Xhi [BATCH][D_IN]
    const f16* __restrict__ Bt,   // WhiT [D_SAE][D_IN]
    const float* __restrict__ b_enc,
    float* __restrict__ out)      // [BATCH][D_SAE]
{
    __shared__ f16 Asm[128 * 32];
    __shared__ f16 Bsm[128 * 32];
    const int tid  = threadIdx.x;
    const int wave = tid >> 6;
    const int lane = tid & 63;
    const int bn = blockIdx.x * 128;
    const int bm = blockIdx.y * 128;

    const int r16  = lane >> 2;       // 0..15 row within staging chunk
    const int kc8  = (lane & 3) * 8;  // f16 k-offset within 32
    const int mrow = lane & 15;
    const int quad = lane >> 4;
    const int wm = (wave & 1) * 64;
    const int wn = (wave >> 1) * 64;

    v4f acc[4][4] = {};

    const f16* gA0 = A  + (size_t)(bm + wave * 32 + r16) * D_IN + kc8;
    const f16* gA1 = gA0 + 16 * D_IN;
    const f16* gB0 = Bt + (size_t)(bn + wave * 32 + r16) * D_IN + kc8;
    const f16* gB1 = gB0 + 16 * D_IN;
    f16* lA0 = &Asm[(wave * 32) * 32];
    f16* lA1 = &Asm[(wave * 32 + 16) * 32];
    f16* lB0 = &Bsm[(wave * 32) * 32];
    f16* lB1 = &Bsm[(wave * 32 + 16) * 32];

    for (int k0 = 0; k0 < D_IN; k0 += 32) {
        __syncthreads();
        async16(gA0 + k0, lA0);
        async16(gA1 + k0, lA1);
        async16(gB0 + k0, lB0);
        async16(gB1 + k0, lB1);
        __syncthreads();

        v8h af[4], bf[4];
#pragma unroll
        for (int i = 0; i < 4; ++i)
            af[i] = *(const v8h*)&Asm[(wm + i * 16 + mrow) * 32 + quad * 8];
#pragma unroll
        for (int j = 0; j < 4; ++j)
            bf[j] = *(const v8h*)&Bsm[(wn + j * 16 + mrow) * 32 + quad * 8];

#pragma unroll
        for (int i = 0; i < 4; ++i)
#pragma unroll
            for (int j = 0; j < 4; ++j)
                acc[i][j] = __builtin_amdgcn_mfma_f32_16x16x32_f16(af[i], bf[j], acc[i][j], 0, 0, 0);
    }

#pragma unroll
    for (int i = 0; i < 4; ++i) {
#pragma unroll
        for (int r = 0; r < 4; ++r) {
            int grow = bm + wm + i * 16 + quad * 4 + r;
            float* op = out + (size_t)grow * D_SAE + bn + wn;
#pragma unroll
            for (int j = 0; j < 4; ++j) {
                int c = j * 16 + mrow;
                float val = acc[i][j][r] + b_enc[bn + wn + c];
                op[c] = val > 0.f ? val : 0.f;
            }
        }
    }
}

// ---------------- fallback exact fp32 VALU GEMM (used only if ws too small) ----------------
__global__ __launch_bounds__(256) void k_gemm_f32(
    const float* __restrict__ X, const float* __restrict__ W,
    const float* __restrict__ b_enc, const float* __restrict__ b_dec,
    float* __restrict__ out)
{
    __shared__ float As[64][36];   // [m][k]
    __shared__ float Bs[32][68];   // [k][n]
    const int tid = threadIdx.x;
    const int tx = tid & 15, ty = tid >> 4;
    const int bm = blockIdx.y * 64, bn = blockIdx.x * 64;
    float acc[4][4] = {};
    for (int k0 = 0; k0 < D_IN; k0 += 32) {
        __syncthreads();
#pragma unroll
        for (int l = 0; l < 8; ++l) {
            int idx = l * 256 + tid;
            int r = idx >> 5, c = idx & 31;
            As[r][c] = X[(size_t)(bm + r) * D_IN + k0 + c] - b_dec[k0 + c];
        }
#pragma unroll
        for (int l = 0; l < 8; ++l) {
            int idx = l * 256 + tid;
            int kk = idx >> 6, c = idx & 63;
            Bs[kk][c] = W[(size_t)(k0 + kk) * D_SAE + bn + c];
        }
        __syncthreads();
#pragma unroll
        for (int kk = 0; kk < 32; ++kk) {
            float a[4];
#pragma unroll
            for (int i = 0; i < 4; ++i) a[i] = As[ty * 4 + i][kk];
            float4 b = *(const float4*)&Bs[kk][tx * 4];
#pragma unroll
            for (int i = 0; i < 4; ++i) {
                acc[i][0] += a[i] * b.x; acc[i][1] += a[i] * b.y;
                acc[i][2] += a[i] * b.z; acc[i][3] += a[i] * b.w;
            }
        }
    }
#pragma unroll
    for (int i = 0; i < 4; ++i) {
        int grow = bm + ty * 4 + i;
        float4 o;
        float* op = out + (size_t)grow * D_SAE + bn + tx * 4;
        o.x = acc[i][0] + b_enc[bn + tx * 4 + 0];
        o.y = acc[i][1] + b_enc[bn + tx * 4 + 1];
        o.z = acc[i][2] + b_enc[bn + tx * 4 + 2];
        o.w = acc[i][3] + b_enc[bn + tx * 4 + 3];
        o.x = o.x > 0.f ? o.x : 0.f; o.y = o.y > 0.f ? o.y : 0.f;
        o.z = o.z > 0.f ? o.z : 0.f; o.w = o.w > 0.f ? o.w : 0.f;
        *(float4*)op = o;
    }
}

// ---------------- per-row: candidate select + exact recompute + topk + rewrite + decode ----------------
__global__ __launch_bounds__(256) void k_topk_decode(
    float* __restrict__ sparse,        // [BATCH][D_SAE]: in approx pre_acts, out final sparse_acts
    const f16* __restrict__ Xhi, const f16* __restrict__ Xlo,
    const f16* __restrict__ WhiT, const f16* __restrict__ WloT,
    const float* __restrict__ b_enc,
    const float* __restrict__ Wdec,    // [D_SAE][D_IN]
    const float* __restrict__ b_dec,
    float* __restrict__ recon,         // [BATCH][D_IN]
    int exact_mode)
{
    const int row = blockIdx.x;
    const int t = threadIdx.x;
    float* rp = sparse + (size_t)row * D_SAE;

    float v[48];
#pragma unroll
    for (int j = 0; j < 48; ++j) v[j] = rp[j * 256 + t];

    __shared__ unsigned hist[256];
    __shared__ unsigned suf[256];
    __shared__ float sh_cutoff;
    __shared__ int sh_ncand;
    __shared__ int sh_nkept;
    __shared__ int   cand_i[256];
    __shared__ float cand_v[256];
    __shared__ unsigned char cand_keep[256];
    __shared__ float kept_v[K_TOP];
    __shared__ int   kept_i[K_TOP];
    __shared__ float xr[D_IN];

    const float margin = exact_mode ? 0.0f : 0.05f;

    hist[t] = 0;
    if (t == 0) { sh_ncand = 0; sh_nkept = 0; }
    __syncthreads();
#pragma unroll
    for (int j = 0; j < 48; ++j) {
        float x = v[j];
        if (x >= 0.25f) {
            int b = (int)(x * 32.0f); if (b > 255) b = 255;
            atomicAdd(&hist[b], 1u);
        }
    }
    __syncthreads();
    suf[t] = hist[t];
    __syncthreads();
    for (int off = 1; off < 256; off <<= 1) {
        unsigned add = (t + off < 256) ? suf[t + off] : 0u;
        __syncthreads();
        suf[t] += add;
        __syncthreads();
    }
    unsigned total0 = suf[0];
    if (total0 >= K_TOP) {
        if (suf[t] >= K_TOP && (t == 255 || suf[t + 1] < K_TOP))
            sh_cutoff = fmaxf((float)t * (1.0f / 32.0f) - margin, 1e-30f);
    } else {
        // level 1: refine (0, 0.25)  [statistically unreachable, kept for robustness]
        __syncthreads();
        hist[t] = 0;
        __syncthreads();
#pragma unroll
        for (int j = 0; j < 48; ++j) {
            float x = v[j];
            if (x > 0.0f && x < 0.25f) {
                int b = (int)(x * 1024.0f); if (b > 255) b = 255;
                atomicAdd(&hist[b], 1u);
            }
        }
        __syncthreads();
        suf[t] = hist[t];
        __syncthreads();
        for (int off = 1; off < 256; off <<= 1) {
            unsigned add = (t + off < 256) ? suf[t + off] : 0u;
            __syncthreads();
            suf[t] += add;
            __syncthreads();
        }
        unsigned need = K_TOP - total0;
        if (suf[0] >= need) {
            if (suf[t] >= need && (t == 255 || suf[t + 1] < need))
                sh_cutoff = fmaxf((float)t * (1.0f / 1024.0f) - margin, 1e-30f);
        } else {
            if (t == 0) sh_cutoff = 1e-30f;  // fewer than K positives: keep all positives
        }
    }
    __syncthreads();
    const float cutoff = sh_cutoff;

    // ---- collect candidate indices (approx >= cutoff) ----
#pragma unroll
    for (int j = 0; j < 48; ++j) {
        float x = v[j];
        if (x >= cutoff) {
            int pos = atomicAdd(&sh_ncand, 1);
            if (pos < 256) { cand_i[pos] = j * 256 + t; cand_v[pos] = x; }
        }
    }
    __syncthreads();
    int ncand = sh_ncand; if (ncand > 256) ncand = 256;

    // ---- exact recompute of candidate pre-activations (fast path only) ----
    if (!exact_mode) {
        for (int k = t; k < D_IN; k += 256)
            xr[k] = (float)Xhi[(size_t)row * D_IN + k] + (float)Xlo[(size_t)row * D_IN + k];
        __syncthreads();
        for (int c = t; c < ncand; c += 256) {
            const f16* wh = WhiT + (size_t)cand_i[c] * D_IN;
            const f16* wl = WloT + (size_t)cand_i[c] * D_IN;
            float acc = 0.f;
            for (int k = 0; k < D_IN; k += 8) {
                v8h hv = *(const v8h*)(wh + k);
                v8h lv = *(const v8h*)(wl + k);
#pragma unroll
                for (int u = 0; u < 8; ++u)
                    acc += xr[k + u] * ((float)hv[u] + (float)lv[u]);
            }
            acc += b_enc[cand_i[c]];
            cand_v[c] = acc > 0.f ? acc : 0.f;
        }
        __syncthreads();
    }

    // ---- exact ranking: (value desc, index asc) — matches lax.top_k tie-break ----
    for (int c = t; c < ncand; c += 256) {
        float vc = cand_v[c]; int ic = cand_i[c];
        int rank = 0;
        for (int m = 0; m < ncand; ++m) {
            float vm = cand_v[m];
            rank += (vm > vc || (vm == vc && cand_i[m] < ic)) ? 1 : 0;
        }
        int keep = rank < K_TOP;
        cand_keep[c] = (unsigned char)keep;
        if (keep) {
            int p = atomicAdd(&sh_nkept, 1);
            kept_v[p] = vc; kept_i[p] = ic;
        }
    }
    __syncthreads();

    // ---- rewrite row: exact value at kept slots, 0 elsewhere ----
#pragma unroll
    for (int j = 0; j < 48; ++j) {
        float x = v[j];
        float outv = 0.f;
        if (x >= cutoff) {
            int gi = j * 256 + t;
            for (int m = 0; m < ncand; ++m)
                if (cand_i[m] == gi) { if (cand_keep[m]) outv = cand_v[m]; break; }
        }
        rp[j * 256 + t] = outv;
    }
    __syncthreads();

    // ---- sparse decode: recon = sum kept_v * Wdec[kept_i,:] + b_dec ----
    int nk = sh_nkept; if (nk > K_TOP) nk = K_TOP;
    float racc[3];
#pragma unroll
    for (int u = 0; u < 3; ++u) racc[u] = b_dec[t + u * 256];
    for (int m = 0; m < nk; ++m) {
        float val = kept_v[m];
        const float* wr = Wdec + (size_t)kept_i[m] * D_IN;
#pragma unroll
        for (int u = 0; u < 3; ++u) racc[u] += val * wr[t + u * 256];
    }
#pragma unroll
    for (int u = 0; u < 3; ++u)
        recon[(size_t)row * D_IN + t + u * 256] = racc[u];
}

extern "C" void kernel_launch(void* const* d_in, const int* in_sizes, int n_in,
                              void* d_out, int out_size, void* d_ws, size_t ws_size,
                              hipStream_t stream) {
    const float* x     = (const float*)d_in[0];
    const float* W_enc = (const float*)d_in[1];
    const float* b_enc = (const float*)d_in[2];
    const float* W_dec = (const float*)d_in[3];
    const float* b_dec = (const float*)d_in[4];
    float* out    = (float*)d_out;
    float* recon  = out;                             // [BATCH][D_IN]
    float* sparse = out + (size_t)BATCH * D_IN;      // [BATCH][D_SAE]

    const size_t xplane = (size_t)BATCH * D_IN;      // 6291456
    const size_t wplane = (size_t)D_SAE * D_IN;      // 9437184
    const size_t need = (2 * xplane + 2 * wplane) * sizeof(f16);  // 62914560 B

    if (d_ws != nullptr && ws_size >= need) {
        f16* xhi  = (f16*)d_ws;
        f16* xlo  = xhi + xplane;
        f16* whiT = xlo + xplane;
        f16* wloT = whiT + wplane;
        k_convert_x<<<xplane / 1024, 256, 0, stream>>>(x, b_dec, xhi, xlo);
        k_convert_wt<<<dim3(D_SAE / 32, D_IN / 32), 256, 0, stream>>>(W_enc, whiT, wloT);
        k_gemm_f16<<<dim3(D_SAE / 128, BATCH / 128), 256, 0, stream>>>(xhi, whiT, b_enc, sparse);
        k_topk_decode<<<BATCH, 256, 0, stream>>>(sparse, xhi, xlo, whiT, wloT,
                                                 b_enc, W_dec, b_dec, recon, 0);
    } else {
        k_gemm_f32<<<dim3(D_SAE / 64, BATCH / 64), 256, 0, stream>>>(x, W_enc, b_enc, b_dec, sparse);
        k_topk_decode<<<BATCH, 256, 0, stream>>>(sparse, nullptr, nullptr, nullptr, nullptr,
                                                 b_enc, W_dec, b_dec, recon, 1);
    }
}

// Round 5
// 1358.169 us; speedup vs baseline: 1.6652x; 1.6652x over previous
//
#include <hip/hip_runtime.h>
#include <hip/hip_fp16.h>
#include <stdint.h>

#define D_IN   768
#define D_SAE  12288
#define BATCH  8192
#define K_TOP  64
#define CAND_MAX 256

typedef _Float16 f16;
typedef _Float16 v8h __attribute__((ext_vector_type(8)));
typedef float v4f __attribute__((ext_vector_type(4)));

// async global->LDS, 16B/lane, wave-uniform LDS base (lane writes base + lane*16B)
__device__ inline void async16(const void* g, void* l) {
    __builtin_amdgcn_global_load_lds(
        (const __attribute__((address_space(1))) unsigned int*)g,
        (__attribute__((address_space(3))) unsigned int*)l, 16, 0, 0);
}

// ---------------- convert x: (x - b_dec) -> f16 hi/lo planes [BATCH][D_IN] ----------------
__global__ __launch_bounds__(256) void k_convert_x(
    const float* __restrict__ x, const float* __restrict__ b_dec,
    f16* __restrict__ xhi, f16* __restrict__ xlo)
{
    int i4 = (blockIdx.x * 256 + threadIdx.x) * 4;
    float4 v = *(const float4*)(x + i4);
    int col = i4 % D_IN;
    float vv[4] = { v.x - b_dec[col], v.y - b_dec[col + 1],
                    v.z - b_dec[col + 2], v.w - b_dec[col + 3] };
    union { short4 s; f16 h[4]; } H, L;
#pragma unroll
    for (int u = 0; u < 4; ++u) {
        H.h[u] = (f16)vv[u];
        L.h[u] = (f16)(vv[u] - (float)H.h[u]);
    }
    *(short4*)(xhi + i4) = H.s;
    *(short4*)(xlo + i4) = L.s;
}

// ---------------- convert+transpose W_enc [D_IN][D_SAE] -> hi/lo planes [D_SAE][D_IN] ----------------
__global__ __launch_bounds__(256) void k_convert_wt(
    const float* __restrict__ W, f16* __restrict__ whiT, f16* __restrict__ wloT)
{
    __shared__ float tile[32][33];
    const int n0 = blockIdx.x * 32;
    const int k0 = blockIdx.y * 32;
    const int c = threadIdx.x & 31;
    const int rr = threadIdx.x >> 5;   // 0..7
#pragma unroll
    for (int s = 0; s < 4; ++s) {
        int r = s * 8 + rr;
        tile[r][c] = W[(size_t)(k0 + r) * D_SAE + n0 + c];
    }
    __syncthreads();
#pragma unroll
    for (int s = 0; s < 4; ++s) {
        int r2 = s * 8 + rr;                 // n within tile
        float v = tile[c][r2];               // W[k0+c][n0+r2]
        f16 hi = (f16)v;
        f16 lo = (f16)(v - (float)hi);
        whiT[(size_t)(n0 + r2) * D_IN + k0 + c] = hi;
        wloT[(size_t)(n0 + r2) * D_IN + k0 + c] = lo;
    }
}

// ---------------- approximate encode GEMM — BYTE-IDENTICAL to round 1 (fp32 output) ----------------
__global__ __launch_bounds__(256) void k_gemm_f16(
    const f16* __restrict__ A,    // Xhi [BATCH][D_IN]
    const f16* __restrict__ Bt,   // WhiT [D_SAE][D_IN]
    const float* __restrict__ b_enc,
    float* __restrict__ out)      // [BATCH][D_SAE]
{
    __shared__ f16 Asm[128 * 32];
    __shared__ f16 Bsm[128 * 32];
    const int tid  = threadIdx.x;
    const int wave = tid >> 6;
    const int lane = tid & 63;
    const int bn = blockIdx.x * 128;
    const int bm = blockIdx.y * 128;

    const int r16  = lane >> 2;       // 0..15 staging row
    const int kc8  = (lane & 3) * 8;  // f16 k-offset within 32
    const int mrow = lane & 15;
    const int quad = lane >> 4;
    const int wm = (wave & 1) * 64;
    const int wn = (wave >> 1) * 64;

    v4f acc[4][4] = {};

    const f16* gA0 = A  + (size_t)(bm + wave * 32 + r16) * D_IN + kc8;
    const f16* gA1 = gA0 + 16 * D_IN;
    const f16* gB0 = Bt + (size_t)(bn + wave * 32 + r16) * D_IN + kc8;
    const f16* gB1 = gB0 + 16 * D_IN;
    f16* lA0 = &Asm[(wave * 32) * 32];
    f16* lA1 = &Asm[(wave * 32 + 16) * 32];
    f16* lB0 = &Bsm[(wave * 32) * 32];
    f16* lB1 = &Bsm[(wave * 32 + 16) * 32];

    for (int k0 = 0; k0 < D_IN; k0 += 32) {
        __syncthreads();
        async16(gA0 + k0, lA0);
        async16(gA1 + k0, lA1);
        async16(gB0 + k0, lB0);
        async16(gB1 + k0, lB1);
        __syncthreads();

        v8h af[4], bf[4];
#pragma unroll
        for (int i = 0; i < 4; ++i)
            af[i] = *(const v8h*)&Asm[(wm + i * 16 + mrow) * 32 + quad * 8];
#pragma unroll
        for (int j = 0; j < 4; ++j)
            bf[j] = *(const v8h*)&Bsm[(wn + j * 16 + mrow) * 32 + quad * 8];

#pragma unroll
        for (int i = 0; i < 4; ++i)
#pragma unroll
            for (int j = 0; j < 4; ++j)
                acc[i][j] = __builtin_amdgcn_mfma_f32_16x16x32_f16(af[i], bf[j], acc[i][j], 0, 0, 0);
    }

#pragma unroll
    for (int i = 0; i < 4; ++i) {
#pragma unroll
        for (int r = 0; r < 4; ++r) {
            int grow = bm + wm + i * 16 + quad * 4 + r;
            float* op = out + (size_t)grow * D_SAE + bn + wn;
#pragma unroll
            for (int j = 0; j < 4; ++j) {
                int c = j * 16 + mrow;
                float val = acc[i][j][r] + b_enc[bn + wn + c];
                op[c] = val > 0.f ? val : 0.f;
            }
        }
    }
}

// ---------------- per-row: round-1 histogram/cutoff/compaction + ROUND-1 sequential recompute + fast scatter ----------------
__global__ __launch_bounds__(256) void k_topk2(
    float* __restrict__ sparse,        // [BATCH][D_SAE]: in fp32 approx pre_acts, out final sparse_acts
    const f16* __restrict__ Xhi, const f16* __restrict__ Xlo,
    const f16* __restrict__ WhiT, const f16* __restrict__ WloT,
    const float* __restrict__ b_enc,
    const float* __restrict__ Wdec,    // [D_SAE][D_IN]
    const float* __restrict__ b_dec,
    float* __restrict__ recon)         // [BATCH][D_IN]
{
    const int row = blockIdx.x;
    const int t = threadIdx.x;
    float* rp = sparse + (size_t)row * D_SAE;

    // ---- load fp32 approx row (round-1 identical) ----
    float v[48];
#pragma unroll
    for (int j = 0; j < 48; ++j) v[j] = rp[j * 256 + t];

    __shared__ unsigned hist[256];
    __shared__ unsigned suf[256];
    __shared__ float sh_cutoff;
    __shared__ int sh_ncand;
    __shared__ int   cand_i[CAND_MAX];
    __shared__ float cand_v[CAND_MAX];
    __shared__ float kept_v[K_TOP];
    __shared__ int   kept_i[K_TOP];
    __shared__ float xr[D_IN];

    const float margin = 0.05f;

    hist[t] = 0;
    if (t == 0) sh_ncand = 0;
    __syncthreads();
#pragma unroll
    for (int j = 0; j < 48; ++j) {
        float x = v[j];
        if (x >= 0.25f) {
            int b = (int)(x * 32.0f); if (b > 255) b = 255;
            atomicAdd(&hist[b], 1u);
        }
    }
    __syncthreads();
    suf[t] = hist[t];
    __syncthreads();
    for (int off = 1; off < 256; off <<= 1) {
        unsigned add = (t + off < 256) ? suf[t + off] : 0u;
        __syncthreads();
        suf[t] += add;
        __syncthreads();
    }
    unsigned total0 = suf[0];
    if (total0 >= K_TOP) {
        if (suf[t] >= K_TOP && (t == 255 || suf[t + 1] < K_TOP))
            sh_cutoff = fmaxf((float)t * (1.0f / 32.0f) - margin, 1e-30f);
    } else {
        // level 1: refine (0, 0.25)  [statistically unreachable, kept for robustness]
        __syncthreads();
        hist[t] = 0;
        __syncthreads();
#pragma unroll
        for (int j = 0; j < 48; ++j) {
            float x = v[j];
            if (x > 0.0f && x < 0.25f) {
                int b = (int)(x * 1024.0f); if (b > 255) b = 255;
                atomicAdd(&hist[b], 1u);
            }
        }
        __syncthreads();
        suf[t] = hist[t];
        __syncthreads();
        for (int off = 1; off < 256; off <<= 1) {
            unsigned add = (t + off < 256) ? suf[t + off] : 0u;
            __syncthreads();
            suf[t] += add;
            __syncthreads();
        }
        unsigned need = K_TOP - total0;
        if (suf[0] >= need) {
            if (suf[t] >= need && (t == 255 || suf[t + 1] < need))
                sh_cutoff = fmaxf((float)t * (1.0f / 1024.0f) - margin, 1e-30f);
        } else {
            if (t == 0) sh_cutoff = 1e-30f;  // fewer than K positives: keep all positives
        }
    }
    __syncthreads();
    const float cutoff = sh_cutoff;

    // ---- collect candidate indices (round-1 identical) ----
#pragma unroll
    for (int j = 0; j < 48; ++j) {
        float x = v[j];
        if (x >= cutoff) {
            int pos = atomicAdd(&sh_ncand, 1);
            if (pos < CAND_MAX) { cand_i[pos] = j * 256 + t; cand_v[pos] = x; }
        }
    }
    __syncthreads();
    int ncand = sh_ncand; if (ncand > CAND_MAX) ncand = CAND_MAX;

    // ---- exact recompute: ROUND-1 BYTE-EXACT (sequential k per thread — rounding
    //      correlated with np reference; do NOT parallelize the k-sum) ----
    for (int k = t; k < D_IN; k += 256)
        xr[k] = (float)Xhi[(size_t)row * D_IN + k] + (float)Xlo[(size_t)row * D_IN + k];
    __syncthreads();
    for (int c = t; c < ncand; c += 256) {
        const f16* wh = WhiT + (size_t)cand_i[c] * D_IN;
        const f16* wl = WloT + (size_t)cand_i[c] * D_IN;
        float acc = 0.f;
        for (int k = 0; k < D_IN; k += 8) {
            v8h hv = *(const v8h*)(wh + k);
            v8h lv = *(const v8h*)(wl + k);
#pragma unroll
            for (int u = 0; u < 8; ++u)
                acc += xr[k + u] * ((float)hv[u] + (float)lv[u]);
        }
        acc += b_enc[cand_i[c]];
        cand_v[c] = acc > 0.f ? acc : 0.f;
    }
    __syncthreads();

    // ---- exact ranking (value desc, index asc), rank-indexed kept store ----
    for (int c = t; c < ncand; c += 256) {
        float vc = cand_v[c]; int ic = cand_i[c];
        int r = 0;
        for (int m = 0; m < ncand; ++m) {
            float vm = cand_v[m];
            r += (vm > vc || (vm == vc && cand_i[m] < ic)) ? 1 : 0;
        }
        if (r < K_TOP) { kept_v[r] = vc; kept_i[r] = ic; }
    }
    __syncthreads();
    int nk = ncand < K_TOP ? ncand : K_TOP;

    // ---- write sparse row: zero-fill then scatter exact values ----
#pragma unroll
    for (int j = 0; j < 12; ++j) {
        float4 z = {0.f, 0.f, 0.f, 0.f};
        *(float4*)(rp + ((size_t)j * 256 + t) * 4) = z;
    }
    __syncthreads();
    if (t < nk) rp[kept_i[t]] = kept_v[t];

    // ---- sparse decode (round-1 identical) ----
    float r0 = b_dec[t], r1 = b_dec[t + 256], r2 = b_dec[t + 512];
    for (int m = 0; m < nk; ++m) {
        float val = kept_v[m];
        const float* wr = Wdec + (size_t)kept_i[m] * D_IN;
        r0 += val * wr[t];
        r1 += val * wr[t + 256];
        r2 += val * wr[t + 512];
    }
    float* rc = recon + (size_t)row * D_IN;
    rc[t] = r0; rc[t + 256] = r1; rc[t + 512] = r2;
}

extern "C" void kernel_launch(void* const* d_in, const int* in_sizes, int n_in,
                              void* d_out, int out_size, void* d_ws, size_t ws_size,
                              hipStream_t stream) {
    const float* x     = (const float*)d_in[0];
    const float* W_enc = (const float*)d_in[1];
    const float* b_enc = (const float*)d_in[2];
    const float* W_dec = (const float*)d_in[3];
    const float* b_dec = (const float*)d_in[4];
    float* out    = (float*)d_out;
    float* recon  = out;                             // [BATCH][D_IN]
    float* sparse = out + (size_t)BATCH * D_IN;      // [BATCH][D_SAE]

    const size_t xplane = (size_t)BATCH * D_IN;      // 6291456
    const size_t wplane = (size_t)D_SAE * D_IN;      // 9437184
    f16* xhi  = (f16*)d_ws;
    f16* xlo  = xhi + xplane;
    f16* whiT = xlo + xplane;
    f16* wloT = whiT + wplane;

    k_convert_x<<<xplane / 1024, 256, 0, stream>>>(x, b_dec, xhi, xlo);
    k_convert_wt<<<dim3(D_SAE / 32, D_IN / 32), 256, 0, stream>>>(W_enc, whiT, wloT);
    k_gemm_f16<<<dim3(D_SAE / 128, BATCH / 128), 256, 0, stream>>>(xhi, whiT, b_enc, sparse);
    k_topk2<<<BATCH, 256, 0, stream>>>(sparse, xhi, xlo, whiT, wloT, b_enc, W_dec, b_dec, recon);
}

// Round 7
// 1240.477 us; speedup vs baseline: 1.8232x; 1.0949x over previous
//
#include <hip/hip_runtime.h>
#include <hip/hip_fp16.h>
#include <stdint.h>

#define D_IN   768
#define D_SAE  12288
#define BATCH  8192
#define K_TOP  64
#define CAND_MAX 256

typedef _Float16 f16;
typedef _Float16 v8h __attribute__((ext_vector_type(8)));
typedef float v4f __attribute__((ext_vector_type(4)));

// async global->LDS, 16B/lane, wave-uniform LDS base (lane writes base + lane*16B)
__device__ inline void async16(const void* g, void* l) {
    __builtin_amdgcn_global_load_lds(
        (const __attribute__((address_space(1))) unsigned int*)g,
        (__attribute__((address_space(3))) unsigned int*)l, 16, 0, 0);
}

// ---------------- convert x: (x - b_dec) -> f16 hi/lo planes [BATCH][D_IN] ----------------
__global__ __launch_bounds__(256) void k_convert_x(
    const float* __restrict__ x, const float* __restrict__ b_dec,
    f16* __restrict__ xhi, f16* __restrict__ xlo)
{
    int i4 = (blockIdx.x * 256 + threadIdx.x) * 4;
    float4 v = *(const float4*)(x + i4);
    int col = i4 % D_IN;
    float vv[4] = { v.x - b_dec[col], v.y - b_dec[col + 1],
                    v.z - b_dec[col + 2], v.w - b_dec[col + 3] };
    union { short4 s; f16 h[4]; } H, L;
#pragma unroll
    for (int u = 0; u < 4; ++u) {
        H.h[u] = (f16)vv[u];
        L.h[u] = (f16)(vv[u] - (float)H.h[u]);
    }
    *(short4*)(xhi + i4) = H.s;
    *(short4*)(xlo + i4) = L.s;
}

// ---------------- convert+transpose W_enc [D_IN][D_SAE] -> hi/lo planes [D_SAE][D_IN] ----------------
__global__ __launch_bounds__(256) void k_convert_wt(
    const float* __restrict__ W, f16* __restrict__ whiT, f16* __restrict__ wloT)
{
    __shared__ float tile[32][33];
    const int n0 = blockIdx.x * 32;
    const int k0 = blockIdx.y * 32;
    const int c = threadIdx.x & 31;
    const int rr = threadIdx.x >> 5;   // 0..7
#pragma unroll
    for (int s = 0; s < 4; ++s) {
        int r = s * 8 + rr;
        tile[r][c] = W[(size_t)(k0 + r) * D_SAE + n0 + c];
    }
    __syncthreads();
#pragma unroll
    for (int s = 0; s < 4; ++s) {
        int r2 = s * 8 + rr;                 // n within tile
        float v = tile[c][r2];               // W[k0+c][n0+r2]
        f16 hi = (f16)v;
        f16 lo = (f16)(v - (float)hi);
        whiT[(size_t)(n0 + r2) * D_IN + k0 + c] = hi;
        wloT[(size_t)(n0 + r2) * D_IN + k0 + c] = lo;
    }
}

// ---------------- approximate encode GEMM (f16 MFMA, 128x128 tile, BK=64) ----------------
// Writes relu(A*Bt^T + b_enc) rounded to f16 (nontemporal) into the FIRST HALF
// of each row's fp32 span in the sparse output region.
__global__ __launch_bounds__(256) void k_gemm_f16(
    const f16* __restrict__ A,    // Xhi [BATCH][D_IN]
    const f16* __restrict__ Bt,   // WhiT [D_SAE][D_IN]
    const float* __restrict__ b_enc,
    f16* __restrict__ outap)
{
    __shared__ f16 Asm[2][128 * 32];
    __shared__ f16 Bsm[2][128 * 32];
    const int tid  = threadIdx.x;
    const int wave = tid >> 6;
    const int lane = tid & 63;
    const int bn = blockIdx.x * 128;
    const int bm = blockIdx.y * 128;

    const int r16  = lane >> 2;       // 0..15 staging row
    const int kc8  = (lane & 3) * 8;  // f16 k-offset within 32
    const int mrow = lane & 15;
    const int quad = lane >> 4;
    const int wm = (wave & 1) * 64;
    const int wn = (wave >> 1) * 64;

    v4f acc[4][4] = {};

    const f16* gA = A  + (size_t)(bm + wave * 32 + r16) * D_IN + kc8;
    const f16* gB = Bt + (size_t)(bn + wave * 32 + r16) * D_IN + kc8;
    f16* lA0  = &Asm[0][(wave * 32) * 32];
    f16* lA0b = &Asm[0][(wave * 32 + 16) * 32];
    f16* lB0  = &Bsm[0][(wave * 32) * 32];
    f16* lB0b = &Bsm[0][(wave * 32 + 16) * 32];
    f16* lA1  = &Asm[1][(wave * 32) * 32];
    f16* lA1b = &Asm[1][(wave * 32 + 16) * 32];
    f16* lB1  = &Bsm[1][(wave * 32) * 32];
    f16* lB1b = &Bsm[1][(wave * 32 + 16) * 32];

    for (int k0 = 0; k0 < D_IN; k0 += 64) {
        __syncthreads();
        async16(gA + k0,               lA0);
        async16(gA + k0 + 16 * D_IN,   lA0b);
        async16(gB + k0,               lB0);
        async16(gB + k0 + 16 * D_IN,   lB0b);
        async16(gA + k0 + 32,              lA1);
        async16(gA + k0 + 32 + 16 * D_IN,  lA1b);
        async16(gB + k0 + 32,              lB1);
        async16(gB + k0 + 32 + 16 * D_IN,  lB1b);
        __syncthreads();

#pragma unroll
        for (int s = 0; s < 2; ++s) {
            v8h af[4], bf[4];
#pragma unroll
            for (int i = 0; i < 4; ++i)
                af[i] = *(const v8h*)&Asm[s][(wm + i * 16 + mrow) * 32 + quad * 8];
#pragma unroll
            for (int j = 0; j < 4; ++j)
                bf[j] = *(const v8h*)&Bsm[s][(wn + j * 16 + mrow) * 32 + quad * 8];
#pragma unroll
            for (int i = 0; i < 4; ++i)
#pragma unroll
                for (int j = 0; j < 4; ++j)
                    acc[i][j] = __builtin_amdgcn_mfma_f32_16x16x32_f16(af[i], bf[j], acc[i][j], 0, 0, 0);
        }
    }

#pragma unroll
    for (int i = 0; i < 4; ++i) {
#pragma unroll
        for (int r = 0; r < 4; ++r) {
            int grow = bm + wm + i * 16 + quad * 4 + r;
            f16* op = outap + (size_t)grow * (2 * D_SAE) + bn + wn;
#pragma unroll
            for (int j = 0; j < 4; ++j) {
                int c = j * 16 + mrow;
                float val = acc[i][j][r] + b_enc[bn + wn + c];
                __builtin_nontemporal_store((f16)(val > 0.f ? val : 0.f), op + c);
            }
        }
    }
}

// ---------------- per-row: histogram/cutoff/compaction + sequential exact recompute + scatter + decode ----------------
__global__ __launch_bounds__(256) void k_topk2(
    float* __restrict__ sparse,        // [BATCH][D_SAE]: in f16 approx (first half), out final sparse_acts
    const f16* __restrict__ Xhi, const f16* __restrict__ Xlo,
    const f16* __restrict__ WhiT, const f16* __restrict__ WloT,
    const float* __restrict__ b_enc,
    const float* __restrict__ Wdec,    // [D_SAE][D_IN]
    const float* __restrict__ b_dec,
    float* __restrict__ recon)         // [BATCH][D_IN]
{
    const int row = blockIdx.x;
    const int t = threadIdx.x;
    float* rp = sparse + (size_t)row * D_SAE;
    const f16* ap = (const f16*)rp;

    // ---- load f16 approx row, 48 per thread, coalesced 16B, nontemporal ----
    v8h av[6];
#pragma unroll
    for (int j = 0; j < 6; ++j)
        av[j] = __builtin_nontemporal_load((const v8h*)(ap + ((size_t)j * 256 + t) * 8));

    __shared__ unsigned hist[256];
    __shared__ unsigned suf[256];
    __shared__ float sh_cutoff;
    __shared__ int sh_ncand;
    __shared__ int   cand_i[CAND_MAX];
    __shared__ float cand_v[CAND_MAX];
    __shared__ float kept_v[K_TOP];
    __shared__ int   kept_i[K_TOP];
    __shared__ float xr[D_IN];

    const float margin = 0.05f;

    hist[t] = 0;
    if (t == 0) sh_ncand = 0;
    __syncthreads();
    // ---- level-0 histogram over [0.25, 8.25), 1/32 bins (round-1/5 proven range) ----
#pragma unroll
    for (int j = 0; j < 6; ++j)
#pragma unroll
        for (int u = 0; u < 8; ++u) {
            float x = (float)av[j][u];
            if (x >= 0.25f) {
                int b = (int)(x * 32.0f); if (b > 255) b = 255;
                atomicAdd(&hist[b], 1u);
            }
        }
    __syncthreads();
    suf[t] = hist[t];
    __syncthreads();
    for (int off = 1; off < 256; off <<= 1) {
        unsigned add = (t + off < 256) ? suf[t + off] : 0u;
        __syncthreads();
        suf[t] += add;
        __syncthreads();
    }
    unsigned total0 = suf[0];
    if (total0 >= K_TOP) {
        if (suf[t] >= K_TOP && (t == 255 || suf[t + 1] < K_TOP))
            sh_cutoff = fmaxf((float)t * (1.0f / 32.0f) - margin, 1e-30f);
    } else {
        // level 1: refine (0, 0.25)  [statistically unreachable, kept for robustness]
        __syncthreads();
        hist[t] = 0;
        __syncthreads();
#pragma unroll
        for (int j = 0; j < 6; ++j)
#pragma unroll
            for (int u = 0; u < 8; ++u) {
                float x = (float)av[j][u];
                if (x > 0.0f && x < 0.25f) {
                    int b = (int)(x * 1024.0f); if (b > 255) b = 255;
                    atomicAdd(&hist[b], 1u);
                }
            }
        __syncthreads();
        suf[t] = hist[t];
        __syncthreads();
        for (int off = 1; off < 256; off <<= 1) {
            unsigned add = (t + off < 256) ? suf[t + off] : 0u;
            __syncthreads();
            suf[t] += add;
            __syncthreads();
        }
        unsigned need = K_TOP - total0;
        if (suf[0] >= need) {
            if (suf[t] >= need && (t == 255 || suf[t + 1] < need))
                sh_cutoff = fmaxf((float)t * (1.0f / 1024.0f) - margin, 1e-30f);
        } else {
            if (t == 0) sh_cutoff = 1e-30f;  // fewer than K positives: keep all positives
        }
    }
    __syncthreads();
    const float cutoff = sh_cutoff;

    // ---- collect candidate indices ----
#pragma unroll
    for (int j = 0; j < 6; ++j)
#pragma unroll
        for (int u = 0; u < 8; ++u) {
            float x = (float)av[j][u];
            if (x >= cutoff) {
                int pos = atomicAdd(&sh_ncand, 1);
                if (pos < CAND_MAX) { cand_i[pos] = (j * 256 + t) * 8 + u; cand_v[pos] = x; }
            }
        }
    __syncthreads();
    int ncand = sh_ncand; if (ncand > CAND_MAX) ncand = CAND_MAX;

    // ---- exact recompute: SEQUENTIAL k per thread — rounding correlated with
    //      the np reference; DO NOT parallelize or reorder this sum ----
    for (int k = t; k < D_IN; k += 256)
        xr[k] = (float)Xhi[(size_t)row * D_IN + k] + (float)Xlo[(size_t)row * D_IN + k];
    __syncthreads();
    for (int c = t; c < ncand; c += 256) {
        const f16* wh = WhiT + (size_t)cand_i[c] * D_IN;
        const f16* wl = WloT + (size_t)cand_i[c] * D_IN;
        float acc = 0.f;
        for (int k = 0; k < D_IN; k += 8) {
            v8h hv = *(const v8h*)(wh + k);
            v8h lv = *(const v8h*)(wl + k);
#pragma unroll
            for (int u = 0; u < 8; ++u)
                acc += xr[k + u] * ((float)hv[u] + (float)lv[u]);
        }
        acc += b_enc[cand_i[c]];
        cand_v[c] = acc > 0.f ? acc : 0.f;
    }
    __syncthreads();

    // ---- exact ranking (value desc, index asc), rank-indexed kept store ----
    for (int c = t; c < ncand; c += 256) {
        float vc = cand_v[c]; int ic = cand_i[c];
        int r = 0;
        for (int m = 0; m < ncand; ++m) {
            float vm = cand_v[m];
            r += (vm > vc || (vm == vc && cand_i[m] < ic)) ? 1 : 0;
        }
        if (r < K_TOP) { kept_v[r] = vc; kept_i[r] = ic; }
    }
    __syncthreads();
    int nk = ncand < K_TOP ? ncand : K_TOP;

    // ---- write sparse row: nontemporal zero-fill then scatter exact values ----
#pragma unroll
    for (int j = 0; j < 12; ++j) {
        v4f z = {0.f, 0.f, 0.f, 0.f};
        __builtin_nontemporal_store(z, (v4f*)(rp + ((size_t)j * 256 + t) * 4));
    }
    __syncthreads();
    if (t < nk) rp[kept_i[t]] = kept_v[t];

    // ---- sparse decode: recon = sum kept_v * Wdec[kept_i,:] + b_dec ----
    float r0 = b_dec[t], r1 = b_dec[t + 256], r2 = b_dec[t + 512];
    for (int m = 0; m < nk; ++m) {
        float val = kept_v[m];
        const float* wr = Wdec + (size_t)kept_i[m] * D_IN;
        r0 += val * wr[t];
        r1 += val * wr[t + 256];
        r2 += val * wr[t + 512];
    }
    float* rc = recon + (size_t)row * D_IN;
    __builtin_nontemporal_store(r0, rc + t);
    __builtin_nontemporal_store(r1, rc + t + 256);
    __builtin_nontemporal_store(r2, rc + t + 512);
}

extern "C" void kernel_launch(void* const* d_in, const int* in_sizes, int n_in,
                              void* d_out, int out_size, void* d_ws, size_t ws_size,
                              hipStream_t stream) {
    const float* x     = (const float*)d_in[0];
    const float* W_enc = (const float*)d_in[1];
    const float* b_enc = (const float*)d_in[2];
    const float* W_dec = (const float*)d_in[3];
    const float* b_dec = (const float*)d_in[4];
    float* out    = (float*)d_out;
    float* recon  = out;                             // [BATCH][D_IN]
    float* sparse = out + (size_t)BATCH * D_IN;      // [BATCH][D_SAE]

    const size_t xplane = (size_t)BATCH * D_IN;      // 6291456
    const size_t wplane = (size_t)D_SAE * D_IN;      // 9437184
    f16* xhi  = (f16*)d_ws;
    f16* xlo  = xhi + xplane;
    f16* whiT = xlo + xplane;
    f16* wloT = whiT + wplane;

    k_convert_x<<<xplane / 1024, 256, 0, stream>>>(x, b_dec, xhi, xlo);
    k_convert_wt<<<dim3(D_SAE / 32, D_IN / 32), 256, 0, stream>>>(W_enc, whiT, wloT);
    k_gemm_f16<<<dim3(D_SAE / 128, BATCH / 128), 256, 0, stream>>>(xhi, whiT, b_enc, (f16*)sparse);
    k_topk2<<<BATCH, 256, 0, stream>>>(sparse, xhi, xlo, whiT, wloT, b_enc, W_dec, b_dec, recon);
}